// Round 20
// baseline (301.445 us; speedup 1.0000x reference)
//
#include <hip/hip_runtime.h>
#include <hip/hip_bf16.h>

typedef __attribute__((ext_vector_type(8))) short s16x8;
typedef __attribute__((ext_vector_type(4))) float f32x4;
typedef unsigned short u16;
typedef unsigned int u32;

constexpr int NN = 50000;
constexpr int NE = 600000;
constexpr int NIDX = 10000;

__device__ inline u16 f2b(float x) {
    __hip_bfloat16 h = __float2bfloat16(x);
    return *(u16*)&h;
}

__device__ inline s16x8 pack8(float4 a, float4 b) {
    s16x8 r;
    r[0] = (short)f2b(a.x); r[1] = (short)f2b(a.y);
    r[2] = (short)f2b(a.z); r[3] = (short)f2b(a.w);
    r[4] = (short)f2b(b.x); r[5] = (short)f2b(b.y);
    r[6] = (short)f2b(b.z); r[7] = (short)f2b(b.w);
    return r;
}

// async global->LDS DMA, 16B per lane: LDS dst = wave-uniform base + lane*16.
__device__ inline void gl_lds16(const void* gptr, void* lptr) {
    __builtin_amdgcn_global_load_lds(
        (const __attribute__((address_space(1))) char*)gptr,
        (__attribute__((address_space(3))) char*)lptr, 16, 0, 0);
}

template <int N> __device__ inline void vmwait() {
    asm volatile("s_waitcnt vmcnt(%0)" :: "n"(N) : "memory");
}
__device__ inline void barrier_nodrains() {
    __builtin_amdgcn_sched_barrier(0);
    __builtin_amdgcn_s_barrier();
    __builtin_amdgcn_sched_barrier(0);
}

// ---------------- setup: padvf | win(vec4) | bcomb | wrg1 | wrg2 | hist(1 atomic) | mark ----
// Zeroing of counters/mark done by hipMemsetAsync before this kernel.

__global__ void k_setup(const float* __restrict__ vf,
                        const float* __restrict__ fc1w, const float* __restrict__ fc2w,
                        const float* __restrict__ reluw,
                        const float* __restrict__ fc1b, const float* __restrict__ fc2b,
                        const float* __restrict__ relub,
                        const float* __restrict__ w1rel, const float* __restrict__ w1root,
                        const float* __restrict__ w2rel, const float* __restrict__ w2root,
                        const int* __restrict__ ei, const int* __restrict__ et,
                        const int* __restrict__ idx,
                        float* __restrict__ vfp, u16* __restrict__ WTin,
                        float* __restrict__ bcomb, u16* __restrict__ WT1, u16* __restrict__ WT2,
                        int* __restrict__ deg_rel,
                        int* __restrict__ mark, int* __restrict__ cnt2, int* __restrict__ list) {
    int b = blockIdx.x, t = threadIdx.x;
    if (b < 6250) {                              // padvf: NN*32 = 1.6M
        int i = b * 256 + t;
        int n = i >> 5, c = i & 31;
        vfp[i] = c < 16 ? vf[n * 16 + c] : 0.f;
    } else if (b < 6350) {                       // win: 8 k per block, 4 c per thread
        int k = (b - 6250) * 8 + (t >> 5);
        int c0 = (t & 31) * 4;
        float4 s = {0.f, 0.f, 0.f, 0.f};
        if (k < 768) {
#pragma unroll 4
            for (int j = 0; j < 128; ++j) {
                float fw = fc2w[k * 128 + j];
                float4 rw = *(const float4*)&reluw[(128 + j) * 128 + c0];
                s.x += fw * rw.x; s.y += fw * rw.y; s.z += fw * rw.z; s.w += fw * rw.w;
            }
        } else if (k < 784) {
            int kk = k - 768;
#pragma unroll 4
            for (int j = 0; j < 128; ++j) {
                float fw = fc1w[kk * 128 + j];
                float4 rw = *(const float4*)&reluw[j * 128 + c0];
                s.x += fw * rw.x; s.y += fw * rw.y; s.z += fw * rw.z; s.w += fw * rw.w;
            }
        }
        WTin[(c0 + 0) * 800 + k] = f2b(s.x);
        WTin[(c0 + 1) * 800 + k] = f2b(s.y);
        WTin[(c0 + 2) * 800 + k] = f2b(s.z);
        WTin[(c0 + 3) * 800 + k] = f2b(s.w);
    } else if (b == 6350) {                      // bcomb
        if (t < 128) {
            int c = t;
            float s = relub[c];
            for (int j = 0; j < 128; ++j) {
                s += fc1b[j] * reluw[j * 128 + c];
                s += fc2b[j] * reluw[(128 + j) * 128 + c];
            }
            bcomb[c] = s;
        }
    } else if (b < 6863) {                       // wrg1: s = b-6351 in [0,512)
        if (t < 128) {
            int s = b - 6351, c = t;
            float v = (s < 384) ? w1rel[(size_t)s * 128 + c] : w1root[(size_t)(s - 384) * 128 + c];
            WT1[c * 512 + s] = f2b(v);
        }
    } else if (b < 7375) {                       // wrg2
        if (t < 128) {
            int s = b - 6863, c = t;
            float v = (s < 384) ? w2rel[(size_t)s * 128 + c] : w2root[(size_t)(s - 384) * 128 + c];
            WT2[c * 512 + s] = f2b(v);
        }
    } else if (b < 9719) {                       // hist: deg_rel only (deg_node derived in alloc)
        int e = (b - 7375) * 256 + t;
        if (e < NE) {
            int dst = ei[NE + e];
            int r = et[e];
            atomicAdd(&deg_rel[r * NN + dst], 1);
        }
    } else {                                     // idx mark/compact
        int i = (b - 9719) * 256 + t;
        if (i < NIDX) {
            int n = idx[i];
            if (atomicExch(&mark[n], 1) == 0) {
                int p = atomicAdd(cnt2, 1);
                list[p] = n;
            }
        }
    }
}

// ---------------- alloc (CSR offsets, degn derived from deg_rel) + norm ----------------

__global__ void k_alloc_norm(int* __restrict__ deg_node, int* __restrict__ baseoff,
                             int* __restrict__ counter, const int* __restrict__ deg_rel,
                             float* __restrict__ normf) {
    int b = blockIdx.x;
    if (b < 196) {
        int i = b * 256 + threadIdx.x;
        int lane = threadIdx.x & 63;
        int d = 0;
        if (i < NN) d = deg_rel[i] + deg_rel[NN + i] + deg_rel[2 * NN + i];
        int scan = d;
        for (int off = 1; off < 64; off <<= 1) {
            int t = __shfl_up(scan, off, 64);
            if (lane >= off) scan += t;
        }
        int total = __shfl(scan, 63, 64);
        int wbase = 0;
        if (lane == 63) wbase = atomicAdd(counter, total);
        wbase = __shfl(wbase, 63, 64);
        if (i < NN) { baseoff[i] = wbase + scan - d; deg_node[i] = d; }
    } else {
        int i = (b - 196) * 256 + threadIdx.x;
        if (i < 3 * NN) normf[i] = 1.0f / (float)max(deg_rel[i], 1);
    }
}

// ---------------- aggregation: 4-way MLP-unrolled gather chain ----------------

template <bool LIST>
__device__ __forceinline__ void agg_body(int outrow, int n, int lane,
                                         const u16* __restrict__ x, u16* __restrict__ A,
                                         const int* __restrict__ elist,
                                         const int* __restrict__ baseoff,
                                         const int* __restrict__ deg_node,
                                         const float* __restrict__ normf) {
    float a0x = 0.f, a0y = 0.f, a1x = 0.f, a1y = 0.f, a2x = 0.f, a2y = 0.f;
    int nb = deg_node[n];
    int b0 = baseoff[n];
    auto ACC = [&](u32 pair, int r) {
        float vx = __uint_as_float((pair & 0xFFFFu) << 16);
        float vy = __uint_as_float((pair >> 16) << 16);
        if (r == 0)      { a0x += vx; a0y += vy; }
        else if (r == 1) { a1x += vx; a1y += vy; }
        else             { a2x += vx; a2y += vy; }
    };
    int i = 0;
    for (; i + 4 <= nb; i += 4) {
        int p0 = elist[b0 + i], p1 = elist[b0 + i + 1];
        int p2 = elist[b0 + i + 2], p3 = elist[b0 + i + 3];
        u32 q0 = *(const u32*)&x[(size_t)(p0 & 0xFFFFF) * 128 + lane * 2];
        u32 q1 = *(const u32*)&x[(size_t)(p1 & 0xFFFFF) * 128 + lane * 2];
        u32 q2 = *(const u32*)&x[(size_t)(p2 & 0xFFFFF) * 128 + lane * 2];
        u32 q3 = *(const u32*)&x[(size_t)(p3 & 0xFFFFF) * 128 + lane * 2];
        ACC(q0, p0 >> 20); ACC(q1, p1 >> 20); ACC(q2, p2 >> 20); ACC(q3, p3 >> 20);
    }
    for (; i < nb; ++i) {
        int p = elist[b0 + i];
        u32 q = *(const u32*)&x[(size_t)(p & 0xFFFFF) * 128 + lane * 2];
        ACC(q, p >> 20);
    }
    float n0 = normf[n], n1 = normf[NN + n], n2 = normf[2 * NN + n];
    u32* Ao = (u32*)&A[(size_t)outrow * 384];
    Ao[lane]        = (u32)f2b(a0x * n0) | ((u32)f2b(a0y * n0) << 16);
    Ao[64 + lane]   = (u32)f2b(a1x * n1) | ((u32)f2b(a1y * n1) << 16);
    Ao[128 + lane]  = (u32)f2b(a2x * n2) | ((u32)f2b(a2y * n2) << 16);
}

__global__ __launch_bounds__(64) void k_agg(const u16* __restrict__ x, u16* __restrict__ A,
                                            const int* __restrict__ elist,
                                            const int* __restrict__ baseoff,
                                            const int* __restrict__ deg_node,
                                            const float* __restrict__ normf) {
    agg_body<false>(blockIdx.x, blockIdx.x, threadIdx.x, x, A, elist, baseoff, deg_node, normf);
}

__global__ __launch_bounds__(64) void k_agg2(const u16* __restrict__ x, u16* __restrict__ A2buf,
                                             const int* __restrict__ elist,
                                             const int* __restrict__ baseoff,
                                             const int* __restrict__ deg_node,
                                             const float* __restrict__ normf,
                                             const int* __restrict__ list,
                                             const int* __restrict__ cnt2) {
    int i = blockIdx.x;
    if (i >= *cnt2) return;
    agg_body<true>(i, list[i], threadIdx.x, x, A2buf, elist, baseoff, deg_node, normf);
}

// ---------------- GEMM body: BM in {64,128}, BK=32, 3 LDS buffers, depth-2
// prefetch, counted vmcnt at no-drain barriers. LIST mode: N=*cntp, indirection --

template <typename TA, int BM, int K1T, int K2T, bool LRELU, bool LIST>
__device__ __forceinline__ void gemm_body(int bid,
                                          const TA* __restrict__ A1, int lda1,
                                          const TA* __restrict__ A2, int lda2,
                                          const u16* __restrict__ WT, int ldwt,
                                          const float* __restrict__ bias,
                                          u16* __restrict__ out, int Nin,
                                          const int* __restrict__ list,
                                          const int* __restrict__ cntp) {
    constexpr int KT = K1T + K2T;
    constexpr int MI = BM / 32;                 // acc rows per wave (2 or 4)
    constexpr int AJJ = BM / 64;                // bf16 A-stage ops per wave (1 or 2)
    constexpr int ABYTES = BM * 32 * (int)sizeof(TA);
    constexpr int TILEB = ABYTES + 8192;
    constexpr int OPW = (sizeof(TA) == 4) ? 6 : (AJJ + 2);  // fp32 only used with BM=64 -> 4; bf16: AJJ+2
    constexpr int OPW_F32 = 4;
    constexpr int OPW_EFF = (sizeof(TA) == 4) ? OPW_F32 : OPW;
    __shared__ alignas(128) char lds[3][TILEB];

    const int N = LIST ? *cntp : Nin;
    const int m0 = bid * BM;
    if (LIST && m0 >= N) return;

    const int tid = threadIdx.x;
    const int w = tid >> 6, lane = tid & 63;
    const int wr = w >> 1, wc = w & 1;
    const int lq = lane >> 4, lr = lane & 15;

    auto stage = [&](int j) {
        char* base = lds[j % 3];
        int kt = j;
        if constexpr (sizeof(TA) == 4) {
            // BM=64 only
#pragma unroll
            for (int jj = 0; jj < 2; ++jj) {
                int row = w * 16 + jj * 8 + (lane >> 3);
                int s = lane & 7;
                int chunk = s ^ (row & 7);
                int rg = min(m0 + row, N - 1);
                const float* g;
                if (kt < K1T) g = (const float*)A1 + (size_t)rg * lda1 + kt * 32 + chunk * 4;
                else          g = (const float*)A2 + (size_t)rg * lda2 + (kt - K1T) * 32 + chunk * 4;
                gl_lds16(g, base + w * 2048 + jj * 1024);
            }
        } else {
#pragma unroll
            for (int jj = 0; jj < AJJ; ++jj) {
                int row = w * (16 * AJJ) + jj * 16 + (lane >> 2);
                int s = lane & 3;
                int chunk = s ^ ((row >> 1) & 3);
                int rg = min(m0 + row, N - 1);
                const u16* g;
                if (kt < K1T) {
                    g = (const u16*)A1 + (size_t)rg * lda1 + kt * 32 + chunk * 8;
                } else {
                    int node = LIST ? list[rg] : rg;
                    g = (const u16*)A2 + (size_t)node * lda2 + (kt - K1T) * 32 + chunk * 8;
                }
                gl_lds16(g, base + w * (1024 * AJJ) + jj * 1024);
            }
        }
#pragma unroll
        for (int jj = 0; jj < 2; ++jj) {
            int col = w * 32 + jj * 16 + (lane >> 2);
            int s = lane & 3;
            int chunk = s ^ ((col >> 1) & 3);
            const u16* g = WT + (size_t)col * ldwt + kt * 32 + chunk * 8;
            gl_lds16(g, base + ABYTES + w * 2048 + jj * 1024);
        }
    };

    f32x4 acc[MI][4] = {};

    auto compute = [&](int j) {
        char* base = lds[j % 3];
        s16x8 af[MI];
#pragma unroll
        for (int i = 0; i < MI; ++i) {
            int row = wr * (BM / 2) + i * 16 + lr;
            if constexpr (sizeof(TA) == 4) {
                int m = row & 7;
                float4 f0 = *(const float4*)(base + row * 128 + (((2 * lq) ^ m) * 16));
                float4 f1 = *(const float4*)(base + row * 128 + (((2 * lq + 1) ^ m) * 16));
                af[i] = pack8(f0, f1);
            } else {
                int sl = lq ^ ((row >> 1) & 3);
                af[i] = *(const s16x8*)(base + row * 64 + sl * 16);
            }
        }
#pragma unroll
        for (int j4 = 0; j4 < 4; ++j4) {
            int col = wc * 64 + j4 * 16 + lr;
            int sl = lq ^ ((col >> 1) & 3);
            s16x8 bf = *(const s16x8*)(base + ABYTES + col * 64 + sl * 16);
#pragma unroll
            for (int i = 0; i < MI; ++i)
                acc[i][j4] = __builtin_amdgcn_mfma_f32_16x16x32_bf16(af[i], bf, acc[i][j4], 0, 0, 0);
        }
    };

    stage(0); stage(1);
#pragma unroll 1
    for (int j = 0; j < KT - 1; ++j) {
        vmwait<OPW_EFF>();
        barrier_nodrains();
        if (j + 2 < KT) stage(j + 2);
        compute(j);
    }
    vmwait<0>();
    barrier_nodrains();
    compute(KT - 1);

#pragma unroll
    for (int i = 0; i < MI; ++i) {
#pragma unroll
        for (int q = 0; q < 4; ++q) {
            int grow = m0 + wr * (BM / 2) + i * 16 + lq * 4 + q;
            if (grow < N) {
                int orow = LIST ? list[grow] : grow;
#pragma unroll
                for (int j = 0; j < 4; ++j) {
                    int col = wc * 64 + j * 16 + lr;
                    float v = acc[i][j][q] + bias[col];
                    if (LRELU) v = v > 0.f ? v : 0.01f * v;
                    out[(size_t)orow * 128 + col] = f2b(v);
                }
            }
        }
    }
}

// ---------------- fused input GEMM + CSR fill ----------------

__global__ __launch_bounds__(256) void k_gin_fill(
        const float* __restrict__ A1, int lda1,
        const float* __restrict__ A2, int lda2,
        const u16* __restrict__ WT, int ldwt,
        const float* __restrict__ bias, u16* __restrict__ out, int N,
        const int* __restrict__ ei, const int* __restrict__ et,
        const int* __restrict__ baseoff, int* __restrict__ cursor,
        int* __restrict__ elist) {
    int b = blockIdx.x, t = threadIdx.x;
    if (b < 782) {
        gemm_body<float, 64, 24, 1, true, false>(b, A1, lda1, A2, lda2, WT, ldwt,
                                                 bias, out, N, nullptr, nullptr);
    } else {
        int e = (b - 782) * 256 + t;
        if (e < NE) {
            int dst = ei[NE + e];
            int src = ei[e];
            int r = et[e];
            int pos = atomicAdd(&cursor[dst], 1);
            elist[baseoff[dst] + pos] = src | (r << 20);
        }
    }
}

__global__ __launch_bounds__(256) void k_gemm_r1(const u16* __restrict__ A1, int lda1,
                                                 const u16* __restrict__ A2, int lda2,
                                                 const u16* __restrict__ WT, int ldwt,
                                                 const float* __restrict__ bias,
                                                 u16* __restrict__ out, int N) {
    gemm_body<u16, 128, 12, 4, false, false>(blockIdx.x, A1, lda1, A2, lda2, WT, ldwt,
                                             bias, out, N, nullptr, nullptr);
}
__global__ __launch_bounds__(256) void k_gemm_r2(const u16* __restrict__ A1, int lda1,
                                                 const u16* __restrict__ A2, int lda2,
                                                 const u16* __restrict__ WT, int ldwt,
                                                 const float* __restrict__ bias,
                                                 u16* __restrict__ out,
                                                 const int* __restrict__ list,
                                                 const int* __restrict__ cnt2) {
    gemm_body<u16, 128, 12, 4, false, true>(blockIdx.x, A1, lda1, A2, lda2, WT, ldwt,
                                            bias, out, NIDX, list, cnt2);
}

// ---------------- final gather + classifier ----------------

__global__ __launch_bounds__(256) void k_out(const u16* __restrict__ h, const int* __restrict__ idx,
                                             const float* __restrict__ fc3w,
                                             const float* __restrict__ fc3b,
                                             float* __restrict__ out, int M) {
    int w = threadIdx.x >> 6;
    int lane = threadIdx.x & 63;
    int row = blockIdx.x * 4 + w;
    if (row >= M) return;
    int n = idx[row];
    u32 pair = *(const u32*)&h[(size_t)n * 128 + lane * 2];
    float v0 = __uint_as_float((pair & 0xFFFFu) << 16);
    float v1 = __uint_as_float((pair >> 16) << 16);
    float4 wv = *(const float4*)&fc3w[lane * 4];
    float s0 = v0 * wv.x + v1 * wv.z;
    float s1 = v0 * wv.y + v1 * wv.w;
    for (int off = 32; off >= 1; off >>= 1) {
        s0 += __shfl_xor(s0, off, 64);
        s1 += __shfl_xor(s1, off, 64);
    }
    if (lane == 0) {
        out[row * 2] = s0 + fc3b[0];
        out[row * 2 + 1] = s1 + fc3b[1];
    }
}

// ---------------- launch ----------------

extern "C" void kernel_launch(void* const* d_in, const int* in_sizes, int n_in,
                              void* d_out, int out_size, void* d_ws, size_t ws_size,
                              hipStream_t stream) {
    const float* vf    = (const float*)d_in[0];
    const float* tf    = (const float*)d_in[1];
    const float* fc1w  = (const float*)d_in[2];
    const float* fc1b  = (const float*)d_in[3];
    const float* fc2w  = (const float*)d_in[4];
    const float* fc2b  = (const float*)d_in[5];
    const float* reluw = (const float*)d_in[6];
    const float* relub = (const float*)d_in[7];
    const float* w1rel = (const float*)d_in[8];
    const float* w1root= (const float*)d_in[9];
    const float* b1    = (const float*)d_in[10];
    const float* w2rel = (const float*)d_in[11];
    const float* w2root= (const float*)d_in[12];
    const float* b2    = (const float*)d_in[13];
    const float* fc3w  = (const float*)d_in[14];
    const float* fc3b  = (const float*)d_in[15];
    const int* ei      = (const int*)d_in[16];
    const int* et      = (const int*)d_in[17];
    const int* idx     = (const int*)d_in[18];
    float* out = (float*)d_out;

    char* W = (char*)d_ws;
    const size_t OFF_WTIN  = 0;          // 204800
    const size_t OFF_WT1   = 204800;     // 131072
    const size_t OFF_WT2   = 335872;     // 131072
    const size_t OFF_BCOMB = 466944;     // 512
    // contiguous memset region: degn | cur | degr | cnt | cnt2 | mark = 1200008 B
    const size_t OFF_DEGN  = 467456;
    const size_t OFF_CUR   = 667456;
    const size_t OFF_DEGR  = 867456;
    const size_t OFF_CNT   = 1467456;
    const size_t OFF_CNT2  = 1467460;
    const size_t OFF_MARK  = 1467464;    // 200000 -> ends 1667464
    const size_t OFF_BASE  = 1667520;
    const size_t OFF_NORM  = 1867520;
    const size_t OFF_ELIST = 2467520;
    const size_t OFF_A     = 4867520;    // 38400000
    const size_t OFF_H0    = 43267520;   // 12800000
    const size_t OFF_H1    = 56067520;   // 12800000
    const size_t OFF_H2    = 68867520;   // 12800000
    const size_t OFF_VFPAD = 81667520;   // 6400000
    const size_t OFF_LIST  = 88067520;   // 40000
    const size_t OFF_A2    = 88107520;   // 7680000 -> total 95787520

    u16* WTin   = (u16*)(W + OFF_WTIN);
    u16* WT1    = (u16*)(W + OFF_WT1);
    u16* WT2    = (u16*)(W + OFF_WT2);
    float* bcomb= (float*)(W + OFF_BCOMB);
    int* degn   = (int*)(W + OFF_DEGN);
    int* cur    = (int*)(W + OFF_CUR);
    int* degr   = (int*)(W + OFF_DEGR);
    int* cnt    = (int*)(W + OFF_CNT);
    int* cnt2   = (int*)(W + OFF_CNT2);
    int* mark   = (int*)(W + OFF_MARK);
    int* base   = (int*)(W + OFF_BASE);
    float* normf= (float*)(W + OFF_NORM);
    int* elist  = (int*)(W + OFF_ELIST);
    u16* Abuf   = (u16*)(W + OFF_A);
    u16* h0     = (u16*)(W + OFF_H0);
    u16* h1     = (u16*)(W + OFF_H1);
    u16* h2     = (u16*)(W + OFF_H2);
    float* vfp  = (float*)(W + OFF_VFPAD);
    int* list   = (int*)(W + OFF_LIST);
    u16* A2buf  = (u16*)(W + OFF_A2);

    const int GRID_R1 = (NN + 127) / 128;      // 391
    const int GRID_R2 = (NIDX + 127) / 128;    // 79

    // 0. zero counters+mark (contiguous) via async memset
    hipMemsetAsync(W + OFF_DEGN, 0, 1200008, stream);

    // 1. setup: padvf | win(vec4) | bcomb | wrg1 | wrg2 | hist | idx mark/compact
    k_setup<<<9759, 256, 0, stream>>>(vf, fc1w, fc2w, reluw, fc1b, fc2b, relub,
                                      w1rel, w1root, w2rel, w2root, ei, et, idx,
                                      vfp, WTin, bcomb, WT1, WT2,
                                      degr, mark, cnt2, list);

    // 2. CSR offsets (degn derived) + norm
    k_alloc_norm<<<782, 256, 0, stream>>>(degn, base, cnt, degr, normf);

    // 3. fused input GEMM (BM=64 fp32) + CSR fill (hides under GEMM)
    k_gin_fill<<<3126, 256, 0, stream>>>(tf, 768, vfp, 32, WTin, 800, bcomb, h0, NN,
                                         ei, et, base, cur, elist);

    // 4. RGCN layer 1 (BM=128)
    k_agg<<<NN, 64, 0, stream>>>(h0, Abuf, elist, base, degn, normf);
    k_gemm_r1<<<GRID_R1, 256, 0, stream>>>(Abuf, 384, h0, 128, WT1, 512, b1, h1, NN);

    // 5. RGCN layer 2 (only idx rows; BM=128)
    k_agg2<<<NIDX, 64, 0, stream>>>(h1, A2buf, elist, base, degn, normf, list, cnt2);
    k_gemm_r2<<<GRID_R2, 256, 0, stream>>>(A2buf, 384, h1, 128, WT2, 512, b2, h2, list, cnt2);

    // 6. classifier on gathered rows
    k_out<<<(NIDX + 3) / 4, 256, 0, stream>>>(h2, idx, fc3w, fc3b, out, NIDX);
}

// Round 21
// 210.721 us; speedup vs baseline: 1.4305x; 1.4305x over previous
//
#include <hip/hip_runtime.h>
#include <hip/hip_bf16.h>

typedef __attribute__((ext_vector_type(8))) short s16x8;
typedef __attribute__((ext_vector_type(4))) float f32x4;
typedef unsigned short u16;
typedef unsigned int u32;

constexpr int NN = 50000;
constexpr int NE = 600000;
constexpr int NIDX = 10000;

__device__ inline u16 f2b(float x) {
    __hip_bfloat16 h = __float2bfloat16(x);
    return *(u16*)&h;
}

__device__ inline s16x8 pack8(float4 a, float4 b) {
    s16x8 r;
    r[0] = (short)f2b(a.x); r[1] = (short)f2b(a.y);
    r[2] = (short)f2b(a.z); r[3] = (short)f2b(a.w);
    r[4] = (short)f2b(b.x); r[5] = (short)f2b(b.y);
    r[6] = (short)f2b(b.z); r[7] = (short)f2b(b.w);
    return r;
}

// async global->LDS DMA, 16B per lane: LDS dst = wave-uniform base + lane*16.
__device__ inline void gl_lds16(const void* gptr, void* lptr) {
    __builtin_amdgcn_global_load_lds(
        (const __attribute__((address_space(1))) char*)gptr,
        (__attribute__((address_space(3))) char*)lptr, 16, 0, 0);
}

template <int N> __device__ inline void vmwait() {
    asm volatile("s_waitcnt vmcnt(%0)" :: "n"(N) : "memory");
}
__device__ inline void barrier_nodrains() {
    __builtin_amdgcn_sched_barrier(0);
    __builtin_amdgcn_s_barrier();
    __builtin_amdgcn_sched_barrier(0);
}

// ---------------- setup: padvf | win(vec4) | bcomb | wrg1 | wrg2 | hist(1 atomic) | mark ----
// Zeroing of counters/mark done by hipMemsetAsync before this kernel.

__global__ void k_setup(const float* __restrict__ vf,
                        const float* __restrict__ fc1w, const float* __restrict__ fc2w,
                        const float* __restrict__ reluw,
                        const float* __restrict__ fc1b, const float* __restrict__ fc2b,
                        const float* __restrict__ relub,
                        const float* __restrict__ w1rel, const float* __restrict__ w1root,
                        const float* __restrict__ w2rel, const float* __restrict__ w2root,
                        const int* __restrict__ ei, const int* __restrict__ et,
                        const int* __restrict__ idx,
                        float* __restrict__ vfp, u16* __restrict__ WTin,
                        float* __restrict__ bcomb, u16* __restrict__ WT1, u16* __restrict__ WT2,
                        int* __restrict__ deg_rel,
                        int* __restrict__ mark, int* __restrict__ cnt2, int* __restrict__ list) {
    int b = blockIdx.x, t = threadIdx.x;
    if (b < 6250) {                              // padvf: NN*32 = 1.6M
        int i = b * 256 + t;
        int n = i >> 5, c = i & 31;
        vfp[i] = c < 16 ? vf[n * 16 + c] : 0.f;
    } else if (b < 6350) {                       // win: 8 k per block, 4 c per thread
        int k = (b - 6250) * 8 + (t >> 5);
        int c0 = (t & 31) * 4;
        float4 s = {0.f, 0.f, 0.f, 0.f};
        if (k < 768) {
#pragma unroll 4
            for (int j = 0; j < 128; ++j) {
                float fw = fc2w[k * 128 + j];
                float4 rw = *(const float4*)&reluw[(128 + j) * 128 + c0];
                s.x += fw * rw.x; s.y += fw * rw.y; s.z += fw * rw.z; s.w += fw * rw.w;
            }
        } else if (k < 784) {
            int kk = k - 768;
#pragma unroll 4
            for (int j = 0; j < 128; ++j) {
                float fw = fc1w[kk * 128 + j];
                float4 rw = *(const float4*)&reluw[j * 128 + c0];
                s.x += fw * rw.x; s.y += fw * rw.y; s.z += fw * rw.z; s.w += fw * rw.w;
            }
        }
        WTin[(c0 + 0) * 800 + k] = f2b(s.x);
        WTin[(c0 + 1) * 800 + k] = f2b(s.y);
        WTin[(c0 + 2) * 800 + k] = f2b(s.z);
        WTin[(c0 + 3) * 800 + k] = f2b(s.w);
    } else if (b == 6350) {                      // bcomb
        if (t < 128) {
            int c = t;
            float s = relub[c];
            for (int j = 0; j < 128; ++j) {
                s += fc1b[j] * reluw[j * 128 + c];
                s += fc2b[j] * reluw[(128 + j) * 128 + c];
            }
            bcomb[c] = s;
        }
    } else if (b < 6863) {                       // wrg1: s = b-6351 in [0,512)
        if (t < 128) {
            int s = b - 6351, c = t;
            float v = (s < 384) ? w1rel[(size_t)s * 128 + c] : w1root[(size_t)(s - 384) * 128 + c];
            WT1[c * 512 + s] = f2b(v);
        }
    } else if (b < 7375) {                       // wrg2
        if (t < 128) {
            int s = b - 6863, c = t;
            float v = (s < 384) ? w2rel[(size_t)s * 128 + c] : w2root[(size_t)(s - 384) * 128 + c];
            WT2[c * 512 + s] = f2b(v);
        }
    } else if (b < 9719) {                       // hist: deg_rel only (deg_node derived in alloc)
        int e = (b - 7375) * 256 + t;
        if (e < NE) {
            int dst = ei[NE + e];
            int r = et[e];
            atomicAdd(&deg_rel[r * NN + dst], 1);
        }
    } else {                                     // idx mark/compact
        int i = (b - 9719) * 256 + t;
        if (i < NIDX) {
            int n = idx[i];
            if (atomicExch(&mark[n], 1) == 0) {
                int p = atomicAdd(cnt2, 1);
                list[p] = n;
            }
        }
    }
}

// ---------------- alloc (CSR offsets, degn derived from deg_rel) + norm ----------------

__global__ void k_alloc_norm(int* __restrict__ deg_node, int* __restrict__ baseoff,
                             int* __restrict__ counter, const int* __restrict__ deg_rel,
                             float* __restrict__ normf) {
    int b = blockIdx.x;
    if (b < 196) {
        int i = b * 256 + threadIdx.x;
        int lane = threadIdx.x & 63;
        int d = 0;
        if (i < NN) d = deg_rel[i] + deg_rel[NN + i] + deg_rel[2 * NN + i];
        int scan = d;
        for (int off = 1; off < 64; off <<= 1) {
            int t = __shfl_up(scan, off, 64);
            if (lane >= off) scan += t;
        }
        int total = __shfl(scan, 63, 64);
        int wbase = 0;
        if (lane == 63) wbase = atomicAdd(counter, total);
        wbase = __shfl(wbase, 63, 64);
        if (i < NN) { baseoff[i] = wbase + scan - d; deg_node[i] = d; }
    } else {
        int i = (b - 196) * 256 + threadIdx.x;
        if (i < 3 * NN) normf[i] = 1.0f / (float)max(deg_rel[i], 1);
    }
}

// ---------------- aggregation (round-11 serial form, measured best — DO NOT unroll) ----

__global__ __launch_bounds__(64) void k_agg(const u16* __restrict__ x, u16* __restrict__ A,
                                            const int* __restrict__ elist,
                                            const int* __restrict__ baseoff,
                                            const int* __restrict__ deg_node,
                                            const float* __restrict__ normf) {
    int n = blockIdx.x;
    int lane = threadIdx.x;
    float a0x = 0.f, a0y = 0.f, a1x = 0.f, a1y = 0.f, a2x = 0.f, a2y = 0.f;
    int nb = deg_node[n];
    int b0 = baseoff[n];
    for (int i = 0; i < nb; ++i) {
        int p = elist[b0 + i];
        int src = p & 0xFFFFF;
        int r = p >> 20;
        u32 pair = *(const u32*)&x[(size_t)src * 128 + lane * 2];
        float vx = __uint_as_float((pair & 0xFFFFu) << 16);
        float vy = __uint_as_float((pair >> 16) << 16);
        if (r == 0)      { a0x += vx; a0y += vy; }
        else if (r == 1) { a1x += vx; a1y += vy; }
        else             { a2x += vx; a2y += vy; }
    }
    float n0 = normf[n], n1 = normf[NN + n], n2 = normf[2 * NN + n];
    u32* Ao = (u32*)&A[(size_t)n * 384];
    Ao[lane]        = (u32)f2b(a0x * n0) | ((u32)f2b(a0y * n0) << 16);
    Ao[64 + lane]   = (u32)f2b(a1x * n1) | ((u32)f2b(a1y * n1) << 16);
    Ao[128 + lane]  = (u32)f2b(a2x * n2) | ((u32)f2b(a2y * n2) << 16);
}

// layer-2 aggregation: only rows in list[0..cnt2), output compacted
__global__ __launch_bounds__(64) void k_agg2(const u16* __restrict__ x, u16* __restrict__ A2buf,
                                             const int* __restrict__ elist,
                                             const int* __restrict__ baseoff,
                                             const int* __restrict__ deg_node,
                                             const float* __restrict__ normf,
                                             const int* __restrict__ list,
                                             const int* __restrict__ cnt2) {
    int i = blockIdx.x;
    if (i >= *cnt2) return;
    int n = list[i];
    int lane = threadIdx.x;
    float a0x = 0.f, a0y = 0.f, a1x = 0.f, a1y = 0.f, a2x = 0.f, a2y = 0.f;
    int nb = deg_node[n];
    int b0 = baseoff[n];
    for (int e = 0; e < nb; ++e) {
        int p = elist[b0 + e];
        int src = p & 0xFFFFF;
        int r = p >> 20;
        u32 pair = *(const u32*)&x[(size_t)src * 128 + lane * 2];
        float vx = __uint_as_float((pair & 0xFFFFu) << 16);
        float vy = __uint_as_float((pair >> 16) << 16);
        if (r == 0)      { a0x += vx; a0y += vy; }
        else if (r == 1) { a1x += vx; a1y += vy; }
        else             { a2x += vx; a2y += vy; }
    }
    float n0 = normf[n], n1 = normf[NN + n], n2 = normf[2 * NN + n];
    u32* Ao = (u32*)&A2buf[(size_t)i * 384];
    Ao[lane]        = (u32)f2b(a0x * n0) | ((u32)f2b(a0y * n0) << 16);
    Ao[64 + lane]   = (u32)f2b(a1x * n1) | ((u32)f2b(a1y * n1) << 16);
    Ao[128 + lane]  = (u32)f2b(a2x * n2) | ((u32)f2b(a2y * n2) << 16);
}

// ---------------- GEMM body: BM=64, BK=32, 3 LDS buffers, depth-2 prefetch,
// counted vmcnt at no-drain barriers. LIST mode: dynamic N=*cntp, indirection ----

template <typename TA, int K1T, int K2T, bool LRELU, bool LIST>
__device__ __forceinline__ void gemm_body(int bid,
                                          const TA* __restrict__ A1, int lda1,
                                          const TA* __restrict__ A2, int lda2,
                                          const u16* __restrict__ WT, int ldwt,
                                          const float* __restrict__ bias,
                                          u16* __restrict__ out, int Nin,
                                          const int* __restrict__ list,
                                          const int* __restrict__ cntp) {
    constexpr int KT = K1T + K2T;
    constexpr int ABYTES = 64 * 32 * (int)sizeof(TA);
    constexpr int TILEB = ABYTES + 8192;
    constexpr int OPW = (sizeof(TA) == 4) ? 4 : 3;
    __shared__ alignas(128) char lds[3][TILEB];

    const int N = LIST ? *cntp : Nin;
    const int m0 = bid * 64;
    if (LIST && m0 >= N) return;

    const int tid = threadIdx.x;
    const int w = tid >> 6, lane = tid & 63;
    const int wr = w >> 1, wc = w & 1;
    const int lq = lane >> 4, lr = lane & 15;

    auto stage = [&](int j) {
        char* base = lds[j % 3];
        int kt = j;
        if constexpr (sizeof(TA) == 4) {
#pragma unroll
            for (int jj = 0; jj < 2; ++jj) {
                int row = w * 16 + jj * 8 + (lane >> 3);
                int s = lane & 7;
                int chunk = s ^ (row & 7);
                int rg = min(m0 + row, N - 1);
                const float* g;
                if (kt < K1T) g = (const float*)A1 + (size_t)rg * lda1 + kt * 32 + chunk * 4;
                else          g = (const float*)A2 + (size_t)rg * lda2 + (kt - K1T) * 32 + chunk * 4;
                gl_lds16(g, base + w * 2048 + jj * 1024);
            }
        } else {
            int row = w * 16 + (lane >> 2);
            int s = lane & 3;
            int chunk = s ^ ((row >> 1) & 3);
            int rg = min(m0 + row, N - 1);
            const u16* g;
            if (kt < K1T) {
                g = (const u16*)A1 + (size_t)rg * lda1 + kt * 32 + chunk * 8;
            } else {
                int node = LIST ? list[rg] : rg;
                g = (const u16*)A2 + (size_t)node * lda2 + (kt - K1T) * 32 + chunk * 8;
            }
            gl_lds16(g, base + w * 1024);
        }
#pragma unroll
        for (int jj = 0; jj < 2; ++jj) {
            int col = w * 32 + jj * 16 + (lane >> 2);
            int s = lane & 3;
            int chunk = s ^ ((col >> 1) & 3);
            const u16* g = WT + (size_t)col * ldwt + kt * 32 + chunk * 8;
            gl_lds16(g, base + ABYTES + w * 2048 + jj * 1024);
        }
    };

    f32x4 acc[2][4] = {};

    auto compute = [&](int j) {
        char* base = lds[j % 3];
        s16x8 af[2];
#pragma unroll
        for (int i = 0; i < 2; ++i) {
            int row = wr * 32 + i * 16 + lr;
            if constexpr (sizeof(TA) == 4) {
                int m = row & 7;
                float4 f0 = *(const float4*)(base + row * 128 + (((2 * lq) ^ m) * 16));
                float4 f1 = *(const float4*)(base + row * 128 + (((2 * lq + 1) ^ m) * 16));
                af[i] = pack8(f0, f1);
            } else {
                int sl = lq ^ ((row >> 1) & 3);
                af[i] = *(const s16x8*)(base + row * 64 + sl * 16);
            }
        }
#pragma unroll
        for (int j4 = 0; j4 < 4; ++j4) {
            int col = wc * 64 + j4 * 16 + lr;
            int sl = lq ^ ((col >> 1) & 3);
            s16x8 bf = *(const s16x8*)(base + ABYTES + col * 64 + sl * 16);
#pragma unroll
            for (int i = 0; i < 2; ++i)
                acc[i][j4] = __builtin_amdgcn_mfma_f32_16x16x32_bf16(af[i], bf, acc[i][j4], 0, 0, 0);
        }
    };

    stage(0); stage(1);
#pragma unroll 1
    for (int j = 0; j < KT - 1; ++j) {
        vmwait<OPW>();
        barrier_nodrains();
        if (j + 2 < KT) stage(j + 2);
        compute(j);
    }
    vmwait<0>();
    barrier_nodrains();
    compute(KT - 1);

#pragma unroll
    for (int i = 0; i < 2; ++i) {
#pragma unroll
        for (int q = 0; q < 4; ++q) {
            int grow = m0 + wr * 32 + i * 16 + lq * 4 + q;
            if (grow < N) {
                int orow = LIST ? list[grow] : grow;
#pragma unroll
                for (int j = 0; j < 4; ++j) {
                    int col = wc * 64 + j * 16 + lr;
                    float v = acc[i][j][q] + bias[col];
                    if (LRELU) v = v > 0.f ? v : 0.01f * v;
                    out[(size_t)orow * 128 + col] = f2b(v);
                }
            }
        }
    }
}

// ---------------- fused input GEMM + CSR fill ----------------

__global__ __launch_bounds__(256) void k_gin_fill(
        const float* __restrict__ A1, int lda1,
        const float* __restrict__ A2, int lda2,
        const u16* __restrict__ WT, int ldwt,
        const float* __restrict__ bias, u16* __restrict__ out, int N,
        const int* __restrict__ ei, const int* __restrict__ et,
        const int* __restrict__ baseoff, int* __restrict__ cursor,
        int* __restrict__ elist) {
    int b = blockIdx.x, t = threadIdx.x;
    if (b < 782) {
        gemm_body<float, 24, 1, true, false>(b, A1, lda1, A2, lda2, WT, ldwt,
                                             bias, out, N, nullptr, nullptr);
    } else {
        int e = (b - 782) * 256 + t;
        if (e < NE) {
            int dst = ei[NE + e];
            int src = ei[e];
            int r = et[e];
            int pos = atomicAdd(&cursor[dst], 1);
            elist[baseoff[dst] + pos] = src | (r << 20);
        }
    }
}

__global__ __launch_bounds__(256) void k_gemm_r1(const u16* __restrict__ A1, int lda1,
                                                 const u16* __restrict__ A2, int lda2,
                                                 const u16* __restrict__ WT, int ldwt,
                                                 const float* __restrict__ bias,
                                                 u16* __restrict__ out, int N) {
    gemm_body<u16, 12, 4, false, false>(blockIdx.x, A1, lda1, A2, lda2, WT, ldwt,
                                        bias, out, N, nullptr, nullptr);
}
__global__ __launch_bounds__(256) void k_gemm_r2(const u16* __restrict__ A1, int lda1,
                                                 const u16* __restrict__ A2, int lda2,
                                                 const u16* __restrict__ WT, int ldwt,
                                                 const float* __restrict__ bias,
                                                 u16* __restrict__ out,
                                                 const int* __restrict__ list,
                                                 const int* __restrict__ cnt2) {
    gemm_body<u16, 12, 4, false, true>(blockIdx.x, A1, lda1, A2, lda2, WT, ldwt,
                                       bias, out, NIDX, list, cnt2);
}

// ---------------- final gather + classifier ----------------

__global__ __launch_bounds__(256) void k_out(const u16* __restrict__ h, const int* __restrict__ idx,
                                             const float* __restrict__ fc3w,
                                             const float* __restrict__ fc3b,
                                             float* __restrict__ out, int M) {
    int w = threadIdx.x >> 6;
    int lane = threadIdx.x & 63;
    int row = blockIdx.x * 4 + w;
    if (row >= M) return;
    int n = idx[row];
    u32 pair = *(const u32*)&h[(size_t)n * 128 + lane * 2];
    float v0 = __uint_as_float((pair & 0xFFFFu) << 16);
    float v1 = __uint_as_float((pair >> 16) << 16);
    float4 wv = *(const float4*)&fc3w[lane * 4];
    float s0 = v0 * wv.x + v1 * wv.z;
    float s1 = v0 * wv.y + v1 * wv.w;
    for (int off = 32; off >= 1; off >>= 1) {
        s0 += __shfl_xor(s0, off, 64);
        s1 += __shfl_xor(s1, off, 64);
    }
    if (lane == 0) {
        out[row * 2] = s0 + fc3b[0];
        out[row * 2 + 1] = s1 + fc3b[1];
    }
}

// ---------------- launch ----------------

extern "C" void kernel_launch(void* const* d_in, const int* in_sizes, int n_in,
                              void* d_out, int out_size, void* d_ws, size_t ws_size,
                              hipStream_t stream) {
    const float* vf    = (const float*)d_in[0];
    const float* tf    = (const float*)d_in[1];
    const float* fc1w  = (const float*)d_in[2];
    const float* fc1b  = (const float*)d_in[3];
    const float* fc2w  = (const float*)d_in[4];
    const float* fc2b  = (const float*)d_in[5];
    const float* reluw = (const float*)d_in[6];
    const float* relub = (const float*)d_in[7];
    const float* w1rel = (const float*)d_in[8];
    const float* w1root= (const float*)d_in[9];
    const float* b1    = (const float*)d_in[10];
    const float* w2rel = (const float*)d_in[11];
    const float* w2root= (const float*)d_in[12];
    const float* b2    = (const float*)d_in[13];
    const float* fc3w  = (const float*)d_in[14];
    const float* fc3b  = (const float*)d_in[15];
    const int* ei      = (const int*)d_in[16];
    const int* et      = (const int*)d_in[17];
    const int* idx     = (const int*)d_in[18];
    float* out = (float*)d_out;

    char* W = (char*)d_ws;
    const size_t OFF_WTIN  = 0;          // 204800
    const size_t OFF_WT1   = 204800;     // 131072
    const size_t OFF_WT2   = 335872;     // 131072
    const size_t OFF_BCOMB = 466944;     // 512
    // contiguous memset region: degn | cur | degr | cnt | cnt2 | mark = 1200008 B
    const size_t OFF_DEGN  = 467456;
    const size_t OFF_CUR   = 667456;
    const size_t OFF_DEGR  = 867456;
    const size_t OFF_CNT   = 1467456;
    const size_t OFF_CNT2  = 1467460;
    const size_t OFF_MARK  = 1467464;    // 200000 -> ends 1667464
    const size_t OFF_BASE  = 1667520;
    const size_t OFF_NORM  = 1867520;
    const size_t OFF_ELIST = 2467520;
    const size_t OFF_A     = 4867520;    // 38400000
    const size_t OFF_H0    = 43267520;   // 12800000
    const size_t OFF_H1    = 56067520;   // 12800000
    const size_t OFF_H2    = 68867520;   // 12800000
    const size_t OFF_VFPAD = 81667520;   // 6400000
    const size_t OFF_LIST  = 88067520;   // 40000
    const size_t OFF_A2    = 88107520;   // 7680000 -> total 95787520

    u16* WTin   = (u16*)(W + OFF_WTIN);
    u16* WT1    = (u16*)(W + OFF_WT1);
    u16* WT2    = (u16*)(W + OFF_WT2);
    float* bcomb= (float*)(W + OFF_BCOMB);
    int* degn   = (int*)(W + OFF_DEGN);
    int* cur    = (int*)(W + OFF_CUR);
    int* degr   = (int*)(W + OFF_DEGR);
    int* cnt    = (int*)(W + OFF_CNT);
    int* cnt2   = (int*)(W + OFF_CNT2);
    int* mark   = (int*)(W + OFF_MARK);
    int* base   = (int*)(W + OFF_BASE);
    float* normf= (float*)(W + OFF_NORM);
    int* elist  = (int*)(W + OFF_ELIST);
    u16* Abuf   = (u16*)(W + OFF_A);
    u16* h0     = (u16*)(W + OFF_H0);
    u16* h1     = (u16*)(W + OFF_H1);
    u16* h2     = (u16*)(W + OFF_H2);
    float* vfp  = (float*)(W + OFF_VFPAD);
    int* list   = (int*)(W + OFF_LIST);
    u16* A2buf  = (u16*)(W + OFF_A2);

    const int GRID_GEMM = (NN + 63) / 64;      // 782
    const int GRID_G2   = (NIDX + 63) / 64;    // 157

    // 0. zero counters+mark (contiguous) via async memset
    hipMemsetAsync(W + OFF_DEGN, 0, 1200008, stream);

    // 1. setup: padvf | win(vec4) | bcomb | wrg1 | wrg2 | hist(1-atomic) | idx mark/compact
    k_setup<<<9759, 256, 0, stream>>>(vf, fc1w, fc2w, reluw, fc1b, fc2b, relub,
                                      w1rel, w1root, w2rel, w2root, ei, et, idx,
                                      vfp, WTin, bcomb, WT1, WT2,
                                      degr, mark, cnt2, list);

    // 2. CSR offsets (degn derived from deg_rel) + norm
    k_alloc_norm<<<782, 256, 0, stream>>>(degn, base, cnt, degr, normf);

    // 3. fused input GEMM (BM=64 fp32) + CSR fill (hides under GEMM)
    k_gin_fill<<<3126, 256, 0, stream>>>(tf, 768, vfp, 32, WTin, 800, bcomb, h0, NN,
                                         ei, et, base, cur, elist);

    // 4. RGCN layer 1 (full; serial agg — measured best, do not unroll)
    k_agg<<<NN, 64, 0, stream>>>(h0, Abuf, elist, base, degn, normf);
    k_gemm_r1<<<GRID_GEMM, 256, 0, stream>>>(Abuf, 384, h0, 128, WT1, 512, b1, h1, NN);

    // 5. RGCN layer 2 (only idx rows)
    k_agg2<<<NIDX, 64, 0, stream>>>(h1, A2buf, elist, base, degn, normf, list, cnt2);
    k_gemm_r2<<<GRID_G2, 256, 0, stream>>>(A2buf, 384, h1, 128, WT2, 512, b2, h2, list, cnt2);

    // 6. classifier on gathered rows
    k_out<<<(NIDX + 3) / 4, 256, 0, stream>>>(h2, idx, fc3w, fc3b, out, NIDX);
}